// Round 1
// baseline (10395.193 us; speedup 1.0000x reference)
//
#include <hip/hip_runtime.h>
#include <hip/hip_bf16.h>
#include <math.h>

#define B_  64
#define S_  256
#define D_  1024
#define H_  1024
#define E_  128
#define O_  512
#define IN_ 1152   // D + E
#define G4_ 4096   // 4*H
#define KU_ 1152   // E + H  (u = [emb(128) | h(1024)])
#define KS_ 8      // k-splits for gate partials (1152 = 8*144)

// ---------------- init: u, c, w_out transpose ----------------
__global__ __launch_bounds__(256) void k_init(
    const float* __restrict__ init_tensor,
    const float* __restrict__ w_out,
    float* __restrict__ u, float* __restrict__ c,
    float* __restrict__ w_out_T)
{
  const int NU = B_ * KU_;     // 73728
  const int NC = B_ * H_;      // 65536
  const int NT = H_ * O_;      // 524288
  const int total = NU + NC + NT;
  for (int idx = blockIdx.x * 256 + threadIdx.x; idx < total; idx += gridDim.x * 256) {
    if (idx < NU) {
      int k = idx % KU_;
      u[idx] = (k < E_) ? init_tensor[k] : 0.f;
    } else if (idx < NU + NC) {
      c[idx - NU] = 0.f;
    } else {
      int i = idx - NU - NC;           // i = o*1024 + k (coalesced read)
      int o = i >> 10, k = i & 1023;
      w_out_T[k * O_ + o] = w_out[i];
    }
  }
}

// ---------------- precompute xwb[t,b][j] = x_t[b] @ w_ih[:, :1024]^T + (b_ih+b_hh) ----------------
// GEMM M=rows(=ch*64), N=4096, K=1024. 128x128 tile, BK=16, 8x8 per thread.
__global__ __launch_bounds__(256) void k_xw(
    const float* __restrict__ hidden,
    const float* __restrict__ w_ih,
    const float* __restrict__ b_ih,
    const float* __restrict__ b_hh,
    float* __restrict__ xwb, int t0, int rows)
{
  __shared__ float a_t[16][132];   // [k][m], padded
  __shared__ float b_t[16][132];   // [k][j], padded
  const int tid = threadIdx.x;
  const int tx = tid & 15, ty = tid >> 4;
  const int m_base = blockIdx.x * 128;
  const int n_base = blockIdx.y * 128;
  float acc[8][8];
#pragma unroll
  for (int i = 0; i < 8; ++i)
#pragma unroll
    for (int j = 0; j < 8; ++j) acc[i][j] = 0.f;

  for (int k0 = 0; k0 < D_; k0 += 16) {
#pragma unroll
    for (int l = 0; l < 2; ++l) {
      int s = tid + l * 256;          // 0..511
      int r = s >> 2, kq = (s & 3) << 2;
      int m = m_base + r;
      float4 v = make_float4(0.f, 0.f, 0.f, 0.f);
      if (m < rows) {
        int t = t0 + (m >> 6), b = m & 63;
        v = *(const float4*)(hidden + ((size_t)b * S_ + t) * D_ + k0 + kq);
      }
      a_t[kq + 0][r] = v.x; a_t[kq + 1][r] = v.y; a_t[kq + 2][r] = v.z; a_t[kq + 3][r] = v.w;
      int j = n_base + r;
      float4 w = *(const float4*)(w_ih + (size_t)j * IN_ + k0 + kq);
      b_t[kq + 0][r] = w.x; b_t[kq + 1][r] = w.y; b_t[kq + 2][r] = w.z; b_t[kq + 3][r] = w.w;
    }
    __syncthreads();
#pragma unroll
    for (int k = 0; k < 16; ++k) {
      float av[8], bv[8];
      *(float4*)&av[0] = *(const float4*)&a_t[k][ty * 4];
      *(float4*)&av[4] = *(const float4*)&a_t[k][64 + ty * 4];
      *(float4*)&bv[0] = *(const float4*)&b_t[k][tx * 4];
      *(float4*)&bv[4] = *(const float4*)&b_t[k][64 + tx * 4];
#pragma unroll
      for (int i = 0; i < 8; ++i)
#pragma unroll
        for (int j = 0; j < 8; ++j)
          acc[i][j] = fmaf(av[i], bv[j], acc[i][j]);
    }
    __syncthreads();
  }
  float bias[8];
#pragma unroll
  for (int cj = 0; cj < 8; ++cj) {
    int col = n_base + ((cj < 4) ? (tx * 4 + cj) : (64 + tx * 4 + cj - 4));
    bias[cj] = b_ih[col] + b_hh[col];
  }
#pragma unroll
  for (int ri = 0; ri < 8; ++ri) {
    int m = m_base + ((ri < 4) ? (ty * 4 + ri) : (64 + ty * 4 + ri - 4));
    if (m < rows) {
      float4 s0 = make_float4(acc[ri][0] + bias[0], acc[ri][1] + bias[1],
                              acc[ri][2] + bias[2], acc[ri][3] + bias[3]);
      float4 s1 = make_float4(acc[ri][4] + bias[4], acc[ri][5] + bias[5],
                              acc[ri][6] + bias[6], acc[ri][7] + bias[7]);
      *(float4*)(xwb + (size_t)m * G4_ + n_base + tx * 4) = s0;
      *(float4*)(xwb + (size_t)m * G4_ + n_base + 64 + tx * 4) = s1;
    }
  }
}

// ---------------- per-step gate partials: gp[ks][b][j] = u[b, kchunk] . Wcat[j, kchunk] ----------------
// grid (64 j-tiles, 8 k-splits), block 256. Wcat[j][k] = k<128 ? w_ih[j][1024+k] : w_hh[j][k-128]
__global__ __launch_bounds__(256) void k_gates(
    const float* __restrict__ u,
    const float* __restrict__ w_ih,
    const float* __restrict__ w_hh,
    float* __restrict__ gp)
{
  __shared__ float u_t[48][68];   // [k][b], padded
  __shared__ float w_t[48][68];   // [k][j], padded
  const int jt = blockIdx.x;      // 0..63
  const int ks = blockIdx.y;      // 0..7
  const int tid = threadIdx.x;
  const int tx = tid & 15, ty = tid >> 4;
  const int j_base = jt * 64;
  float acc[4][4];
#pragma unroll
  for (int i = 0; i < 4; ++i)
#pragma unroll
    for (int j = 0; j < 4; ++j) acc[i][j] = 0.f;

  for (int sub = 0; sub < 3; ++sub) {
    const int k0 = ks * 144 + sub * 48;
#pragma unroll
    for (int l = 0; l < 3; ++l) {
      int s = tid + l * 256;        // 0..767
      int row = s / 12;             // 0..63
      int kq = (s % 12) * 4;        // 0..44
      float4 v = *(const float4*)(u + (size_t)row * KU_ + k0 + kq);
      u_t[kq + 0][row] = v.x; u_t[kq + 1][row] = v.y; u_t[kq + 2][row] = v.z; u_t[kq + 3][row] = v.w;
      int kg = k0 + kq;
      int j = j_base + row;
      const float* src = (kg < E_) ? (w_ih + (size_t)j * IN_ + D_ + kg)
                                   : (w_hh + (size_t)j * H_ + (kg - E_));
      float4 w = *(const float4*)src;
      w_t[kq + 0][row] = w.x; w_t[kq + 1][row] = w.y; w_t[kq + 2][row] = w.z; w_t[kq + 3][row] = w.w;
    }
    __syncthreads();
#pragma unroll 16
    for (int k = 0; k < 48; ++k) {
      float uv[4], wv[4];
      *(float4*)uv = *(const float4*)&u_t[k][ty * 4];
      *(float4*)wv = *(const float4*)&w_t[k][tx * 4];
#pragma unroll
      for (int i = 0; i < 4; ++i)
#pragma unroll
        for (int j = 0; j < 4; ++j)
          acc[i][j] = fmaf(uv[i], wv[j], acc[i][j]);
    }
    __syncthreads();
  }
#pragma unroll
  for (int i = 0; i < 4; ++i) {
    int b = ty * 4 + i;
    *(float4*)(gp + ((size_t)ks * B_ + b) * G4_ + j_base + tx * 4) =
        make_float4(acc[i][0], acc[i][1], acc[i][2], acc[i][3]);
  }
}

// ---------------- per-step: reduce gates, LSTM cell, logits partials ----------------
// grid 64: bg = blk&7 (8 b's), sl = blk>>3 (128-wide jj slice == logits k-slice)
__global__ __launch_bounds__(256) void k_cell(
    const float* __restrict__ xwb,
    const float* __restrict__ gp,
    float* __restrict__ u,
    float* __restrict__ c,
    const float* __restrict__ w_out_T,
    float* __restrict__ lp,
    int trel)
{
  __shared__ float h_lds[8][128];
  const int bg = blockIdx.x & 7;
  const int sl = blockIdx.x >> 3;
  const int tid = threadIdx.x;
#pragma unroll
  for (int r = 0; r < 4; ++r) {
    int p = tid + r * 256;          // 0..1023
    int bl = p >> 7, jjl = p & 127;
    int b = bg * 8 + bl;
    int jj = sl * 128 + jjl;
    float g4[4];
#pragma unroll
    for (int g = 0; g < 4; ++g) {
      int j = g * H_ + jj;
      float v = xwb[((size_t)trel * B_ + b) * G4_ + j];
#pragma unroll
      for (int s8 = 0; s8 < 8; ++s8)
        v += gp[((size_t)s8 * B_ + b) * G4_ + j];
      g4[g] = v;
    }
    float iv = 1.f / (1.f + expf(-g4[0]));
    float fv = 1.f / (1.f + expf(-g4[1]));
    float gv = tanhf(g4[2]);
    float ov = 1.f / (1.f + expf(-g4[3]));
    float cc = fv * c[(size_t)b * H_ + jj] + iv * gv;
    c[(size_t)b * H_ + jj] = cc;
    float hv = ov * tanhf(cc);
    u[(size_t)b * KU_ + E_ + jj] = hv;
    h_lds[bl][jjl] = hv;
  }
  __syncthreads();
  float a0[8], a1[8];
#pragma unroll
  for (int bl = 0; bl < 8; ++bl) { a0[bl] = 0.f; a1[bl] = 0.f; }
  for (int kc = 0; kc < 128; kc += 4) {
    float hb[8][4];
#pragma unroll
    for (int bl = 0; bl < 8; ++bl)
      *(float4*)hb[bl] = *(const float4*)&h_lds[bl][kc];
#pragma unroll
    for (int kk = 0; kk < 4; ++kk) {
      int krow = sl * 128 + kc + kk;
      float w0 = w_out_T[(size_t)krow * O_ + tid];
      float w1 = w_out_T[(size_t)krow * O_ + tid + 256];
#pragma unroll
      for (int bl = 0; bl < 8; ++bl) {
        a0[bl] = fmaf(hb[bl][kk], w0, a0[bl]);
        a1[bl] = fmaf(hb[bl][kk], w1, a1[bl]);
      }
    }
  }
#pragma unroll
  for (int bl = 0; bl < 8; ++bl) {
    int b = bg * 8 + bl;
    lp[((size_t)sl * B_ + b) * O_ + tid]       = a0[bl];
    lp[((size_t)sl * B_ + b) * O_ + tid + 256] = a1[bl];
  }
}

// ---------------- per-step: reduce logits, masked store, argmax (first-index), emb gather ----------------
__global__ __launch_bounds__(256) void k_amax(
    const float* __restrict__ lp,
    const float* __restrict__ b_out,
    const float* __restrict__ emb_table,
    const int* __restrict__ seq_lens,
    float* __restrict__ u,
    float* __restrict__ out,
    int t)
{
  __shared__ float sv[256];
  __shared__ int   si[256];
  const int b = blockIdx.x;
  const int tid = threadIdx.x;
  float v0 = b_out[tid];
  float v1 = b_out[tid + 256];
#pragma unroll
  for (int sl = 0; sl < 8; ++sl) {
    v0 += lp[((size_t)sl * B_ + b) * O_ + tid];
    v1 += lp[((size_t)sl * B_ + b) * O_ + tid + 256];
  }
  int len = seq_lens[b];
  float* orow = out + ((size_t)b * S_ + t) * O_;
  bool live = (t < len);
  orow[tid]       = live ? v0 : 0.f;
  orow[tid + 256] = live ? v1 : 0.f;
  // first-index argmax (matches jnp.argmax tie rule)
  float bv = (v1 > v0) ? v1 : v0;
  int   bi = (v1 > v0) ? (tid + 256) : tid;
  sv[tid] = bv; si[tid] = bi;
  __syncthreads();
  for (int s = 128; s > 0; s >>= 1) {
    if (tid < s) {
      float ov = sv[tid + s]; int oi = si[tid + s];
      if (ov > sv[tid] || (ov == sv[tid] && oi < si[tid])) { sv[tid] = ov; si[tid] = oi; }
    }
    __syncthreads();
  }
  int idx = si[0];
  if (tid < E_) u[(size_t)b * KU_ + tid] = emb_table[(size_t)idx * E_ + tid];
}

extern "C" void kernel_launch(void* const* d_in, const int* in_sizes, int n_in,
                              void* d_out, int out_size, void* d_ws, size_t ws_size,
                              hipStream_t stream) {
  const float* hidden      = (const float*)d_in[0];
  const float* init_tensor = (const float*)d_in[1];
  const float* emb_table   = (const float*)d_in[2];
  const float* w_ih        = (const float*)d_in[3];
  const float* w_hh        = (const float*)d_in[4];
  const float* b_ih        = (const float*)d_in[5];
  const float* b_hh        = (const float*)d_in[6];
  const float* w_out       = (const float*)d_in[7];
  const float* b_out       = (const float*)d_in[8];
  const int*   seq_lens    = (const int*)d_in[9];
  float* out = (float*)d_out;
  float* ws  = (float*)d_ws;

  const size_t U_OFF  = 0;
  const size_t C_OFF  = U_OFF + (size_t)B_ * KU_;
  const size_t GP_OFF = C_OFF + (size_t)B_ * H_;
  const size_t LP_OFF = GP_OFF + (size_t)KS_ * B_ * G4_;
  const size_t WT_OFF = LP_OFF + (size_t)8 * B_ * O_;
  const size_t XW_OFF = WT_OFF + (size_t)H_ * O_;   // ~11.5 MB fixed

  long long avail = (long long)(ws_size / 4) - (long long)XW_OFF;
  long long chl = avail / ((long long)B_ * G4_);
  int CH = (int)(chl < 1 ? 1 : (chl > S_ ? S_ : chl));

  k_init<<<dim3(2592), dim3(256), 0, stream>>>(init_tensor, w_out,
                                               ws + U_OFF, ws + C_OFF, ws + WT_OFF);

  for (int t0 = 0; t0 < S_; t0 += CH) {
    int ch = (S_ - t0 < CH) ? (S_ - t0) : CH;
    int rows = ch * B_;
    dim3 pg((rows + 127) / 128, G4_ / 128);
    k_xw<<<pg, dim3(256), 0, stream>>>(hidden, w_ih, b_ih, b_hh, ws + XW_OFF, t0, rows);
    for (int t = t0; t < t0 + ch; ++t) {
      k_gates<<<dim3(64, KS_), dim3(256), 0, stream>>>(ws + U_OFF, w_ih, w_hh, ws + GP_OFF);
      k_cell<<<dim3(64), dim3(256), 0, stream>>>(ws + XW_OFF, ws + GP_OFF, ws + U_OFF,
                                                 ws + C_OFF, ws + WT_OFF, ws + LP_OFF, t - t0);
      k_amax<<<dim3(B_), dim3(256), 0, stream>>>(ws + LP_OFF, b_out, emb_table, seq_lens,
                                                 ws + U_OFF, out, t);
    }
  }
}